// Round 3
// baseline (185.998 us; speedup 1.0000x reference)
//
#include <hip/hip_runtime.h>
#include <stdint.h>
#include <stddef.h>

// NMI loss: x,y (64,1,512,512) f32 -> downsample ::2 -> +threefry noise*1e-4
// -> 24-bin joint hist per batch -> NMI -> -clip(mean,-1,1).
//
// Noise reproduces JAX's threefry2x32-20 stream (jax_threefry_partitionable
// default). Fast path: noise |delta_t| <= 6.54e-3 bin-units, so samples with
// frac(bin-coord) in [MARGIN, 1-MARGIN] are provably noise-invariant -> no
// threefry. Boundary samples (~3.2%) compact into an LDS queue, processed
// densely in phase 2 with the exact noisy path (verified absmax==0, R1/R2).
//
// R3: single fused kernel (hist+reduce+final via agent-scope tickets),
// float4 loads (2 samples / 16B lane), plain-store partials (no big memset).

#define NB 24
#define NBINS 576          // 24*24
#define NBATCH 64
#define SPB 65536          // samples per batch = 256*256
#define HIST_BPB 16        // hist blocks per batch
#define HIST_THREADS 512
#define PER_BLOCK 4096     // SPB / HIST_BPB
#define QCAP 1024          // LDS queue capacity (expected load ~131)
#define MARGIN 0.008f      // > 6.54e-3 worst-case noise swing in bin units

// ws layout
#define PART_ELEMS (NBATCH * HIST_BPB * NBINS)        // 589824 u32
#define CTR_OFF   ((size_t)PART_ELEMS * 4)            // 2359296
#define GCTR_OFF  (CTR_OFF + 256)                     // after ctr[64]
#define NMI_OFF   (CTR_OFF + 512)

__host__ __device__ __forceinline__ uint32_t rotl32_(uint32_t x, uint32_t r) {
  return (x << r) | (x >> (32u - r));
}

// Threefry-2x32, 20 rounds (JAX semantics). x0,x1 carry counts in, bits out.
__host__ __device__ inline void threefry2x32_(uint32_t k0, uint32_t k1,
                                              uint32_t& x0, uint32_t& x1) {
  const uint32_t k2 = k0 ^ k1 ^ 0x1BD11BDAu;
  x0 += k0; x1 += k1;
#define TFR(r) { x0 += x1; x1 = rotl32_(x1, (r)); x1 ^= x0; }
  TFR(13u) TFR(15u) TFR(26u) TFR(6u)
  x0 += k1; x1 += k2 + 1u;
  TFR(17u) TFR(29u) TFR(16u) TFR(24u)
  x0 += k2; x1 += k0 + 2u;
  TFR(13u) TFR(15u) TFR(26u) TFR(6u)
  x0 += k0; x1 += k1 + 3u;
  TFR(17u) TFR(29u) TFR(16u) TFR(24u)
  x0 += k1; x1 += k2 + 4u;
  TFR(13u) TFR(15u) TFR(26u) TFR(6u)
  x0 += k2; x1 += k0 + 5u;
#undef TFR
}

// XLA ErfInv f32 (Giles polynomial) — matches jax.lax.erf_inv lowering.
__device__ __forceinline__ float erfinv32_(float x) {
  float w = -log1pf(-x * x);
  float p;
  if (w < 5.0f) {
    w -= 2.5f;
    p =  2.81022636e-08f;
    p = fmaf(p, w,  3.43273939e-07f);
    p = fmaf(p, w, -3.5233877e-06f);
    p = fmaf(p, w, -4.39150654e-06f);
    p = fmaf(p, w,  0.00021858087f);
    p = fmaf(p, w, -0.00125372503f);
    p = fmaf(p, w, -0.00417768164f);
    p = fmaf(p, w,  0.246640727f);
    p = fmaf(p, w,  1.50140941f);
  } else {
    w = sqrtf(w) - 3.0f;
    p = -0.000200214257f;
    p = fmaf(p, w,  0.000100950558f);
    p = fmaf(p, w,  0.00134934322f);
    p = fmaf(p, w, -0.00367342844f);
    p = fmaf(p, w,  0.00573950773f);
    p = fmaf(p, w, -0.0076224613f);
    p = fmaf(p, w,  0.00943887047f);
    p = fmaf(p, w,  1.00167406f);
    p = fmaf(p, w,  2.83297682f);
  }
  return p * x;
}

__device__ __forceinline__ float tf_normal_(uint32_t ka, uint32_t kb, uint32_t n) {
  uint32_t x0 = 0u, x1 = n;          // counter hi=0 (n < 2^32), lo=n
  threefry2x32_(ka, kb, x0, x1);
  const uint32_t bits = x0 ^ x1;     // 32-bit partitionable output
  float f = __uint_as_float((bits >> 9) | 0x3F800000u) - 1.0f;  // [0,1)
  const float lo = -0.99999994f;     // nextafter(-1,0) in f32
  float u = f * 2.0f + lo;           // f*(hi-lo)+lo, hi-lo rounds to 2.0f
  u = fmaxf(lo, u);
  return 1.41421356f * erfinv32_(u); // sqrt(2) in f32
}

__global__ __launch_bounds__(HIST_THREADS) void nmi_fused_kernel(
    const float* __restrict__ x, const float* __restrict__ y,
    uint32_t* __restrict__ part, uint32_t* __restrict__ ctr,
    uint32_t* __restrict__ gctr, float* __restrict__ nmi_arr,
    float* __restrict__ out,
    uint32_t nk1a, uint32_t nk1b, uint32_t nk2a, uint32_t nk2b) {
  __shared__ uint32_t h[NBINS];
  __shared__ uint16_t q[QCAP];
  __shared__ uint32_t qn;
  __shared__ int islast, glast;
  __shared__ float joint[NBINS];
  __shared__ float xh[NB];
  __shared__ float yh[NB];
  __shared__ float red_mi[8];
  __shared__ float red_h[8];

  const int tid = threadIdx.x;
  for (int t = tid; t < NBINS; t += HIST_THREADS) h[t] = 0u;
  if (tid == 0) qn = 0u;
  __syncthreads();

  const int b    = blockIdx.x / HIST_BPB;
  const int blk  = blockIdx.x % HIST_BPB;
  const int base = blk * PER_BLOCK;
  const float* __restrict__ xb = x + (size_t)b * 262144;  // 512*512
  const float* __restrict__ yb = y + (size_t)b * 262144;
  const uint32_t nbase = (uint32_t)b * (uint32_t)SPB;

  // Phase 1: fast path, 2 samples per float4 lane-load (16B/lane).
  #pragma unroll
  for (int k = 0; k < PER_BLOCK / (2 * HIST_THREADS); ++k) {
    const int p  = k * HIST_THREADS + tid;    // pair index in [0, 2048)
    const int s0 = base + 2 * p;              // even sample; s1 = s0+1
    const int hh = s0 >> 8;                   // row in 256x256
    const int ww = s0 & 255;                  // even col
    const int src = (hh << 10) + (ww << 1);   // 16B-aligned (ww even)
    const float4 xv4 = *reinterpret_cast<const float4*>(xb + src);
    const float4 yv4 = *reinterpret_cast<const float4*>(yb + src);
    #pragma unroll
    for (int e = 0; e < 2; ++e) {
      const float xv = e ? xv4.z : xv4.x;     // elements src, src+2
      const float yv = e ? yv4.z : yv4.x;
      const int   i  = 2 * p + e;             // sample idx within block
      const float tx = fminf(fmaxf((xv + 1.0f) * 0.5f, 0.001f), 0.999f) * 24.0f;
      const float ty = fminf(fmaxf((yv + 1.0f) * 0.5f, 0.001f), 0.999f) * 24.0f;
      const float fx = floorf(tx), fy = floorf(ty);
      const float rx = tx - fx,   ry = ty - fy;
      // t in [0.024, 23.976] -> (int)fx,(int)fy already in [0,23]
      const bool safe = (rx >= MARGIN) & (rx <= 1.0f - MARGIN) &
                        (ry >= MARGIN) & (ry <= 1.0f - MARGIN);
      if (safe) {
        atomicAdd(&h[(int)fx * NB + (int)fy], 1u);
      } else {
        const uint32_t qi = atomicAdd(&qn, 1u);
        if (qi < QCAP) {
          q[qi] = (uint16_t)i;
        } else {
          // overflow fallback (statistically unreachable): exact inline
          const uint32_t n = nbase + (uint32_t)(base + i);
          const float xn = xv + tf_normal_(nk1a, nk1b, n) * 1e-4f;
          const float yn = yv + tf_normal_(nk2a, nk2b, n) * 1e-4f;
          const float vx = fminf(fmaxf((xn + 1.0f) * 0.5f, 0.001f), 0.999f);
          const float vy = fminf(fmaxf((yn + 1.0f) * 0.5f, 0.001f), 0.999f);
          int bx = (int)floorf(vx * 24.0f);
          int by = (int)floorf(vy * 24.0f);
          bx = bx < 0 ? 0 : (bx > 23 ? 23 : bx);
          by = by < 0 ? 0 : (by > 23 ? 23 : by);
          atomicAdd(&h[bx * NB + by], 1u);
        }
      }
    }
  }
  __syncthreads();

  // Phase 2: dense exact path for boundary samples (all lanes active).
  const uint32_t nq = qn < QCAP ? qn : (uint32_t)QCAP;
  for (uint32_t j = tid; j < nq; j += HIST_THREADS) {
    const int i = (int)q[j];
    const int s = base + i;
    const int src = ((s >> 8) << 10) + ((s & 255) << 1);
    const uint32_t n = nbase + (uint32_t)s;
    const float xn = xb[src] + tf_normal_(nk1a, nk1b, n) * 1e-4f;
    const float yn = yb[src] + tf_normal_(nk2a, nk2b, n) * 1e-4f;
    const float vx = fminf(fmaxf((xn + 1.0f) * 0.5f, 0.001f), 0.999f);
    const float vy = fminf(fmaxf((yn + 1.0f) * 0.5f, 0.001f), 0.999f);
    int bx = (int)floorf(vx * 24.0f);
    int by = (int)floorf(vy * 24.0f);
    bx = bx < 0 ? 0 : (bx > 23 ? 23 : bx);
    by = by < 0 ? 0 : (by > 23 ? 23 : by);
    atomicAdd(&h[bx * NB + by], 1u);
  }
  __syncthreads();

  // Write per-block partial (agent-coherent stores; no init needed).
  uint32_t* gp = part + (size_t)(b * HIST_BPB + blk) * NBINS;
  for (int t = tid; t < NBINS; t += HIST_THREADS)
    __hip_atomic_store(&gp[t], h[t], __ATOMIC_RELAXED,
                       __HIP_MEMORY_SCOPE_AGENT);
  __syncthreads();  // drains vmcnt -> all block stores at coherence point

  if (tid == 0) {
    const uint32_t t = __hip_atomic_fetch_add(&ctr[b], 1u, __ATOMIC_ACQ_REL,
                                              __HIP_MEMORY_SCOPE_AGENT);
    islast = (t == (uint32_t)(HIST_BPB - 1));
  }
  __syncthreads();
  if (!islast) return;

  // ---- Last block of this batch: reduce 16 partials -> NMI[b] ----
  const uint32_t* pb = part + (size_t)b * HIST_BPB * NBINS;
  for (int t = tid; t < NBINS; t += HIST_THREADS) {
    uint32_t c = 0;
    #pragma unroll
    for (int sb = 0; sb < HIST_BPB; ++sb)
      c += __hip_atomic_load(&pb[sb * NBINS + t], __ATOMIC_RELAXED,
                             __HIP_MEMORY_SCOPE_AGENT);
    joint[t] = (float)c * (1.0f / 65536.0f);   // total==65536 exactly
  }
  __syncthreads();

  if (tid < NB) {
    float sx = 0.f, sy = 0.f;
    for (int j = 0; j < NB; ++j) {
      sx += joint[tid * NB + j];   // x_hist
      sy += joint[j * NB + tid];   // y_hist
    }
    xh[tid] = sx; yh[tid] = sy;
  }
  __syncthreads();

  float mi_part = 0.f;
  for (int t = tid; t < NBINS; t += HIST_THREADS) {
    const int i = t / NB, j = t % NB;
    const float je = joint[t] + 1e-5f;
    const float pe = (xh[i] + 1e-5f) * (yh[j] + 1e-5f);
    mi_part += je * (logf(je) - logf(pe));
  }
  float h_part = 0.f;
  if (tid < NB) {
    const float e = xh[tid] + 1e-5f;
    h_part = -(e * logf(e));                        // hx term
  } else if (tid >= 64 && tid < 64 + NB) {
    const float e = yh[tid - 64] + 1e-5f;
    h_part = -(e * logf(e));                        // hy term
  }

  for (int o = 32; o > 0; o >>= 1) {
    mi_part += __shfl_down(mi_part, o);
    h_part  += __shfl_down(h_part, o);
  }
  const int wid  = tid >> 6;
  const int lane = tid & 63;
  if (lane == 0) { red_mi[wid] = mi_part; red_h[wid] = h_part; }
  __syncthreads();

  if (tid == 0) {
    float mi = 0.f, se = 0.f;
    #pragma unroll
    for (int w = 0; w < HIST_THREADS / 64; ++w) { mi += red_mi[w]; se += red_h[w]; }
    float nmi = (se < 1e-10f) ? 0.0f : (2.0f * mi / se);
    nmi = fminf(fmaxf(nmi, -1.0f), 1.0f);
    __hip_atomic_store(&nmi_arr[b], nmi, __ATOMIC_RELEASE,
                       __HIP_MEMORY_SCOPE_AGENT);
    const uint32_t t2 = __hip_atomic_fetch_add(gctr, 1u, __ATOMIC_ACQ_REL,
                                               __HIP_MEMORY_SCOPE_AGENT);
    glast = (t2 == (uint32_t)(NBATCH - 1));
  }
  __syncthreads();

  // ---- Very last batch-block: mean over 64 NMIs -> output ----
  if (glast && tid < 64) {
    float v = __hip_atomic_load(&nmi_arr[tid], __ATOMIC_ACQUIRE,
                                __HIP_MEMORY_SCOPE_AGENT);
    for (int o = 32; o > 0; o >>= 1) v += __shfl_down(v, o);
    if (tid == 0) {
      float m = v * (1.0f / 64.0f);                  // mean (exact /2^6)
      m = fminf(fmaxf(m, -1.0f), 1.0f);
      out[0] = -m;
    }
  }
}

extern "C" void kernel_launch(void* const* d_in, const int* in_sizes, int n_in,
                              void* d_out, int out_size, void* d_ws, size_t ws_size,
                              hipStream_t stream) {
  const float* x = (const float*)d_in[0];
  const float* y = (const float*)d_in[1];
  float* out = (float*)d_out;

  uint32_t* part = (uint32_t*)d_ws;
  uint32_t* ctr  = (uint32_t*)((char*)d_ws + CTR_OFF);
  uint32_t* gctr = (uint32_t*)((char*)d_ws + GCTR_OFF);
  float*    nmi  = (float*)((char*)d_ws + NMI_OFF);

  // Host-side key derivation:
  // jax.random.split(jax.random.key(42)) under threefry_partitionable:
  //   nk_i = threefry2x32((0,42), count=(hi=0, lo=i)), both output words.
  uint32_t nk1a = 0u, nk1b = 0u; threefry2x32_(0u, 42u, nk1a, nk1b);
  uint32_t nk2a = 0u, nk2b = 1u; threefry2x32_(0u, 42u, nk2a, nk2b);

  // Only the tickets need zeroing (ctr[64] + gctr): 260 bytes.
  hipMemsetAsync((char*)d_ws + CTR_OFF, 0, 260, stream);
  nmi_fused_kernel<<<NBATCH * HIST_BPB, HIST_THREADS, 0, stream>>>(
      x, y, part, ctr, gctr, nmi, out, nk1a, nk1b, nk2a, nk2b);
}

// Round 4
// 178.666 us; speedup vs baseline: 1.0410x; 1.0410x over previous
//
#include <hip/hip_runtime.h>
#include <stdint.h>
#include <stddef.h>

// NMI loss: x,y (64,1,512,512) f32 -> downsample ::2 -> +threefry noise*1e-4
// -> 24-bin joint hist per batch -> NMI -> -clip(mean,-1,1).
//
// Noise reproduces JAX's threefry2x32-20 stream (jax_threefry_partitionable
// default). Fast path: noise |delta_t| <= 6.54e-3 bin-units, so samples with
// frac(bin-coord) in [MARGIN, 1-MARGIN] are provably noise-invariant -> no
// threefry. Boundary samples (~3.2%) compact into an LDS queue, processed
// densely in phase 2 with the exact noisy path (verified absmax==0, R1-R3).
//
// R4: ONE block per batch (64 blocks x 1024 thr) -> whole joint hist lives in
// LDS; no cross-block merge, no global hist atomics, no partials. Per-batch
// NMI computed in-block; final mean via the 64-op agent ticket (the O(1024)
// per-block ACQ_REL tickets of R3 stalled ~75us in L2 cache-maintenance:
// VALUBusy 5.9%, HBM 0.35% -- agent fences cost a full L2 wb/inv per use).

#define NB 24
#define NBINS 576          // 24*24
#define NBATCH 64
#define SPB 65536          // samples per batch = 256*256
#define THREADS 1024
#define QCAP 4096          // expected boundary load ~2100, sigma~45
#define MARGIN 0.008f      // > 6.54e-3 worst-case noise swing in bin units

__host__ __device__ __forceinline__ uint32_t rotl32_(uint32_t x, uint32_t r) {
  return (x << r) | (x >> (32u - r));
}

// Threefry-2x32, 20 rounds (JAX semantics). x0,x1 carry counts in, bits out.
__host__ __device__ inline void threefry2x32_(uint32_t k0, uint32_t k1,
                                              uint32_t& x0, uint32_t& x1) {
  const uint32_t k2 = k0 ^ k1 ^ 0x1BD11BDAu;
  x0 += k0; x1 += k1;
#define TFR(r) { x0 += x1; x1 = rotl32_(x1, (r)); x1 ^= x0; }
  TFR(13u) TFR(15u) TFR(26u) TFR(6u)
  x0 += k1; x1 += k2 + 1u;
  TFR(17u) TFR(29u) TFR(16u) TFR(24u)
  x0 += k2; x1 += k0 + 2u;
  TFR(13u) TFR(15u) TFR(26u) TFR(6u)
  x0 += k0; x1 += k1 + 3u;
  TFR(17u) TFR(29u) TFR(16u) TFR(24u)
  x0 += k1; x1 += k2 + 4u;
  TFR(13u) TFR(15u) TFR(26u) TFR(6u)
  x0 += k2; x1 += k0 + 5u;
#undef TFR
}

// XLA ErfInv f32 (Giles polynomial) — matches jax.lax.erf_inv lowering.
__device__ __forceinline__ float erfinv32_(float x) {
  float w = -log1pf(-x * x);
  float p;
  if (w < 5.0f) {
    w -= 2.5f;
    p =  2.81022636e-08f;
    p = fmaf(p, w,  3.43273939e-07f);
    p = fmaf(p, w, -3.5233877e-06f);
    p = fmaf(p, w, -4.39150654e-06f);
    p = fmaf(p, w,  0.00021858087f);
    p = fmaf(p, w, -0.00125372503f);
    p = fmaf(p, w, -0.00417768164f);
    p = fmaf(p, w,  0.246640727f);
    p = fmaf(p, w,  1.50140941f);
  } else {
    w = sqrtf(w) - 3.0f;
    p = -0.000200214257f;
    p = fmaf(p, w,  0.000100950558f);
    p = fmaf(p, w,  0.00134934322f);
    p = fmaf(p, w, -0.00367342844f);
    p = fmaf(p, w,  0.00573950773f);
    p = fmaf(p, w, -0.0076224613f);
    p = fmaf(p, w,  0.00943887047f);
    p = fmaf(p, w,  1.00167406f);
    p = fmaf(p, w,  2.83297682f);
  }
  return p * x;
}

__device__ __forceinline__ float tf_normal_(uint32_t ka, uint32_t kb, uint32_t n) {
  uint32_t x0 = 0u, x1 = n;          // counter hi=0 (n < 2^32), lo=n
  threefry2x32_(ka, kb, x0, x1);
  const uint32_t bits = x0 ^ x1;     // 32-bit partitionable output
  float f = __uint_as_float((bits >> 9) | 0x3F800000u) - 1.0f;  // [0,1)
  const float lo = -0.99999994f;     // nextafter(-1,0) in f32
  float u = f * 2.0f + lo;           // f*(hi-lo)+lo, hi-lo rounds to 2.0f
  u = fmaxf(lo, u);
  return 1.41421356f * erfinv32_(u); // sqrt(2) in f32
}

__global__ __launch_bounds__(THREADS) void nmi_fused_kernel(
    const float* __restrict__ x, const float* __restrict__ y,
    uint32_t* __restrict__ gctr, float* __restrict__ nmi_arr,
    float* __restrict__ out,
    uint32_t nk1a, uint32_t nk1b, uint32_t nk2a, uint32_t nk2b) {
  __shared__ uint32_t h[NBINS];
  __shared__ uint16_t q[QCAP];
  __shared__ uint32_t qn;
  __shared__ float joint[NBINS];
  __shared__ float xh[NB];
  __shared__ float yh[NB];
  __shared__ float red_mi[16];
  __shared__ float red_h[16];
  __shared__ int glast;

  const int tid = threadIdx.x;
  const int b   = blockIdx.x;            // one block == one batch
  for (int t = tid; t < NBINS; t += THREADS) h[t] = 0u;
  if (tid == 0) qn = 0u;
  __syncthreads();

  const float* __restrict__ xb = x + (size_t)b * 262144;  // 512*512
  const float* __restrict__ yb = y + (size_t)b * 262144;
  const uint32_t nbase = (uint32_t)b * (uint32_t)SPB;

  // Phase 1: fast path. Bin w/o noise; provably noise-invariant unless the
  // fractional bin coordinate is within MARGIN of a boundary.
  #pragma unroll 4
  for (int k = 0; k < SPB / THREADS; ++k) {
    const int s = k * THREADS + tid;          // sample index in [0, 65536)
    const int src = ((s >> 8) << 10) + ((s & 255) << 1);  // (2h)*512 + 2w
    const float xv = xb[src];
    const float yv = yb[src];
    const float tx = fminf(fmaxf((xv + 1.0f) * 0.5f, 0.001f), 0.999f) * 24.0f;
    const float ty = fminf(fmaxf((yv + 1.0f) * 0.5f, 0.001f), 0.999f) * 24.0f;
    const float fx = floorf(tx), fy = floorf(ty);
    const float rx = tx - fx,   ry = ty - fy;
    // t in [0.024, 23.976] -> (int)fx,(int)fy already in [0,23]
    const bool safe = (rx >= MARGIN) & (rx <= 1.0f - MARGIN) &
                      (ry >= MARGIN) & (ry <= 1.0f - MARGIN);
    if (safe) {
      atomicAdd(&h[(int)fx * NB + (int)fy], 1u);
    } else {
      const uint32_t qi = atomicAdd(&qn, 1u);
      if (qi < QCAP) {
        q[qi] = (uint16_t)s;
      } else {
        // overflow fallback (statistically unreachable): exact inline
        const uint32_t n = nbase + (uint32_t)s;
        const float xn = xv + tf_normal_(nk1a, nk1b, n) * 1e-4f;
        const float yn = yv + tf_normal_(nk2a, nk2b, n) * 1e-4f;
        const float vx = fminf(fmaxf((xn + 1.0f) * 0.5f, 0.001f), 0.999f);
        const float vy = fminf(fmaxf((yn + 1.0f) * 0.5f, 0.001f), 0.999f);
        int bx = (int)floorf(vx * 24.0f);
        int by = (int)floorf(vy * 24.0f);
        bx = bx < 0 ? 0 : (bx > 23 ? 23 : bx);
        by = by < 0 ? 0 : (by > 23 ? 23 : by);
        atomicAdd(&h[bx * NB + by], 1u);
      }
    }
  }
  __syncthreads();

  // Phase 2: dense exact path for boundary samples (all lanes active).
  const uint32_t nq = qn < QCAP ? qn : (uint32_t)QCAP;
  for (uint32_t j = tid; j < nq; j += THREADS) {
    const int s = (int)q[j];
    const int src = ((s >> 8) << 10) + ((s & 255) << 1);
    const uint32_t n = nbase + (uint32_t)s;
    const float xn = xb[src] + tf_normal_(nk1a, nk1b, n) * 1e-4f;
    const float yn = yb[src] + tf_normal_(nk2a, nk2b, n) * 1e-4f;
    const float vx = fminf(fmaxf((xn + 1.0f) * 0.5f, 0.001f), 0.999f);
    const float vy = fminf(fmaxf((yn + 1.0f) * 0.5f, 0.001f), 0.999f);
    int bx = (int)floorf(vx * 24.0f);
    int by = (int)floorf(vy * 24.0f);
    bx = bx < 0 ? 0 : (bx > 23 ? 23 : bx);
    by = by < 0 ? 0 : (by > 23 ? 23 : by);
    atomicAdd(&h[bx * NB + by], 1u);
  }
  __syncthreads();

  // ---- NMI for this batch, entirely in-block ----
  for (int t = tid; t < NBINS; t += THREADS)
    joint[t] = (float)h[t] * (1.0f / 65536.0f);   // total==65536 exactly
  __syncthreads();

  if (tid < NB) {
    float sx = 0.f, sy = 0.f;
    for (int j = 0; j < NB; ++j) {
      sx += joint[tid * NB + j];   // x_hist
      sy += joint[j * NB + tid];   // y_hist
    }
    xh[tid] = sx; yh[tid] = sy;
  }
  __syncthreads();

  float mi_part = 0.f;
  for (int t = tid; t < NBINS; t += THREADS) {
    const int i = t / NB, j = t % NB;
    const float je = joint[t] + 1e-5f;
    const float pe = (xh[i] + 1e-5f) * (yh[j] + 1e-5f);
    mi_part += je * (logf(je) - logf(pe));
  }
  float h_part = 0.f;
  if (tid < NB) {
    const float e = xh[tid] + 1e-5f;
    h_part = -(e * logf(e));                        // hx term
  } else if (tid >= 64 && tid < 64 + NB) {
    const float e = yh[tid - 64] + 1e-5f;
    h_part = -(e * logf(e));                        // hy term
  }

  for (int o = 32; o > 0; o >>= 1) {
    mi_part += __shfl_down(mi_part, o);
    h_part  += __shfl_down(h_part, o);
  }
  const int wid  = tid >> 6;
  const int lane = tid & 63;
  if (lane == 0) { red_mi[wid] = mi_part; red_h[wid] = h_part; }
  __syncthreads();

  if (tid == 0) {
    float mi = 0.f, se = 0.f;
    #pragma unroll
    for (int w = 0; w < THREADS / 64; ++w) { mi += red_mi[w]; se += red_h[w]; }
    float nmi = (se < 1e-10f) ? 0.0f : (2.0f * mi / se);
    nmi = fminf(fmaxf(nmi, -1.0f), 1.0f);
    __hip_atomic_store(&nmi_arr[b], nmi, __ATOMIC_RELEASE,
                       __HIP_MEMORY_SCOPE_AGENT);
    // 64 total agent ACQ_REL ops across the grid (R2-proven cheap; the
    // O(1024) version of this was R3's 75us stall).
    const uint32_t t2 = __hip_atomic_fetch_add(gctr, 1u, __ATOMIC_ACQ_REL,
                                               __HIP_MEMORY_SCOPE_AGENT);
    glast = (t2 == (uint32_t)(NBATCH - 1));
  }
  __syncthreads();

  // ---- Very last block: mean over 64 NMIs -> output ----
  if (glast && tid < 64) {
    float v = __hip_atomic_load(&nmi_arr[tid], __ATOMIC_ACQUIRE,
                                __HIP_MEMORY_SCOPE_AGENT);
    for (int o = 32; o > 0; o >>= 1) v += __shfl_down(v, o);
    if (tid == 0) {
      float m = v * (1.0f / 64.0f);                  // mean (exact /2^6)
      m = fminf(fmaxf(m, -1.0f), 1.0f);
      out[0] = -m;
    }
  }
}

extern "C" void kernel_launch(void* const* d_in, const int* in_sizes, int n_in,
                              void* d_out, int out_size, void* d_ws, size_t ws_size,
                              hipStream_t stream) {
  const float* x = (const float*)d_in[0];
  const float* y = (const float*)d_in[1];
  float* out = (float*)d_out;

  // ws layout: gctr u32 @0 | nmi_arr f32[64] @256
  uint32_t* gctr = (uint32_t*)d_ws;
  float*    nmi  = (float*)((char*)d_ws + 256);

  // Host-side key derivation:
  // jax.random.split(jax.random.key(42)) under threefry_partitionable:
  //   nk_i = threefry2x32((0,42), count=(hi=0, lo=i)), both output words.
  uint32_t nk1a = 0u, nk1b = 0u; threefry2x32_(0u, 42u, nk1a, nk1b);
  uint32_t nk2a = 0u, nk2b = 1u; threefry2x32_(0u, 42u, nk2a, nk2b);

  hipMemsetAsync(gctr, 0, 4, stream);   // only the ticket needs zeroing
  nmi_fused_kernel<<<NBATCH, THREADS, 0, stream>>>(
      x, y, gctr, nmi, out, nk1a, nk1b, nk2a, nk2b);
}

// Round 7
// 148.760 us; speedup vs baseline: 1.2503x; 1.2010x over previous
//
#include <hip/hip_runtime.h>
#include <stdint.h>
#include <stddef.h>

// NMI loss: x,y (64,1,512,512) f32 -> downsample ::2 -> +threefry noise*1e-4
// -> 24-bin joint hist per batch -> NMI -> -clip(mean,-1,1).
//
// Noise reproduces JAX's threefry2x32-20 stream (jax_threefry_partitionable
// default). Fast path: noise |delta_t| <= 6.54e-3 bin-units, so samples with
// frac(bin-coord) in [MARGIN, 1-MARGIN] are provably noise-invariant -> no
// threefry. Boundary samples (~3.2%) compact into an LDS queue, processed
// densely in phase 2 with the exact noisy path (verified absmax==0, R1-R4).
//
// R5/R6/R7 (resubmit x2 after acquisition timeouts): two launches, zero
// memsets, zero agent fences.
//  k1 hist: 256 blocks x 1024 thr (full chip; R4's 64-block version idled
//     75% of CUs -> 70us; R3's 1024 agent tickets stalled L2 -> 80us).
//     Partials via plain stores; kernel boundary provides visibility.
//  k2 reduce: ONE block, wave-per-batch (4 rounds), no barriers in the batch
//     loop, final mean in-block.

#define NB 24
#define NBINS 576          // 24*24
#define NBATCH 64
#define SPB 65536          // samples per batch = 256*256
#define HIST_BPB 4         // hist blocks per batch
#define HIST_THREADS 1024
#define PER_BLOCK 16384    // SPB / HIST_BPB
#define QCAP 4096          // expected boundary load ~524 (sigma ~23)
#define MARGIN 0.008f      // > 6.54e-3 worst-case noise swing in bin units

__host__ __device__ __forceinline__ uint32_t rotl32_(uint32_t x, uint32_t r) {
  return (x << r) | (x >> (32u - r));
}

// Threefry-2x32, 20 rounds (JAX semantics). x0,x1 carry counts in, bits out.
__host__ __device__ inline void threefry2x32_(uint32_t k0, uint32_t k1,
                                              uint32_t& x0, uint32_t& x1) {
  const uint32_t k2 = k0 ^ k1 ^ 0x1BD11BDAu;
  x0 += k0; x1 += k1;
#define TFR(r) { x0 += x1; x1 = rotl32_(x1, (r)); x1 ^= x0; }
  TFR(13u) TFR(15u) TFR(26u) TFR(6u)
  x0 += k1; x1 += k2 + 1u;
  TFR(17u) TFR(29u) TFR(16u) TFR(24u)
  x0 += k2; x1 += k0 + 2u;
  TFR(13u) TFR(15u) TFR(26u) TFR(6u)
  x0 += k0; x1 += k1 + 3u;
  TFR(17u) TFR(29u) TFR(16u) TFR(24u)
  x0 += k1; x1 += k2 + 4u;
  TFR(13u) TFR(15u) TFR(26u) TFR(6u)
  x0 += k2; x1 += k0 + 5u;
#undef TFR
}

// XLA ErfInv f32 (Giles polynomial) — matches jax.lax.erf_inv lowering.
__device__ __forceinline__ float erfinv32_(float x) {
  float w = -log1pf(-x * x);
  float p;
  if (w < 5.0f) {
    w -= 2.5f;
    p =  2.81022636e-08f;
    p = fmaf(p, w,  3.43273939e-07f);
    p = fmaf(p, w, -3.5233877e-06f);
    p = fmaf(p, w, -4.39150654e-06f);
    p = fmaf(p, w,  0.00021858087f);
    p = fmaf(p, w, -0.00125372503f);
    p = fmaf(p, w, -0.00417768164f);
    p = fmaf(p, w,  0.246640727f);
    p = fmaf(p, w,  1.50140941f);
  } else {
    w = sqrtf(w) - 3.0f;
    p = -0.000200214257f;
    p = fmaf(p, w,  0.000100950558f);
    p = fmaf(p, w,  0.00134934322f);
    p = fmaf(p, w, -0.00367342844f);
    p = fmaf(p, w,  0.00573950773f);
    p = fmaf(p, w, -0.0076224613f);
    p = fmaf(p, w,  0.00943887047f);
    p = fmaf(p, w,  1.00167406f);
    p = fmaf(p, w,  2.83297682f);
  }
  return p * x;
}

__device__ __forceinline__ float tf_normal_(uint32_t ka, uint32_t kb, uint32_t n) {
  uint32_t x0 = 0u, x1 = n;          // counter hi=0 (n < 2^32), lo=n
  threefry2x32_(ka, kb, x0, x1);
  const uint32_t bits = x0 ^ x1;     // 32-bit partitionable output
  float f = __uint_as_float((bits >> 9) | 0x3F800000u) - 1.0f;  // [0,1)
  const float lo = -0.99999994f;     // nextafter(-1,0) in f32
  float u = f * 2.0f + lo;           // f*(hi-lo)+lo, hi-lo rounds to 2.0f
  u = fmaxf(lo, u);
  return 1.41421356f * erfinv32_(u); // sqrt(2) in f32
}

__global__ __launch_bounds__(HIST_THREADS) void nmi_hist_kernel(
    const float* __restrict__ x, const float* __restrict__ y,
    uint32_t* __restrict__ part,
    uint32_t nk1a, uint32_t nk1b, uint32_t nk2a, uint32_t nk2b) {
  __shared__ uint32_t h[NBINS];
  __shared__ uint16_t q[QCAP];
  __shared__ uint32_t qn;

  const int tid = threadIdx.x;
  for (int t = tid; t < NBINS; t += HIST_THREADS) h[t] = 0u;
  if (tid == 0) qn = 0u;
  __syncthreads();

  const int b    = blockIdx.x >> 2;          // batch
  const int blk  = blockIdx.x & 3;           // sub-block within batch
  const int base = blk * PER_BLOCK;
  const float* __restrict__ xb = x + (size_t)b * 262144;  // 512*512
  const float* __restrict__ yb = y + (size_t)b * 262144;
  const uint32_t nbase = (uint32_t)b * (uint32_t)SPB;

  // Phase 1: fast path. Bin w/o noise; provably noise-invariant unless the
  // fractional bin coordinate is within MARGIN of a boundary.
  #pragma unroll 4
  for (int k = 0; k < PER_BLOCK / HIST_THREADS; ++k) {
    const int s = base + k * HIST_THREADS + tid;   // sample in [0, 65536)
    const int src = ((s >> 8) << 10) + ((s & 255) << 1);  // (2h)*512 + 2w
    const float xv = xb[src];
    const float yv = yb[src];
    const float tx = fminf(fmaxf((xv + 1.0f) * 0.5f, 0.001f), 0.999f) * 24.0f;
    const float ty = fminf(fmaxf((yv + 1.0f) * 0.5f, 0.001f), 0.999f) * 24.0f;
    const float fx = floorf(tx), fy = floorf(ty);
    const float rx = tx - fx,   ry = ty - fy;
    // t in [0.024, 23.976] -> (int)fx,(int)fy already in [0,23]
    const bool safe = (rx >= MARGIN) & (rx <= 1.0f - MARGIN) &
                      (ry >= MARGIN) & (ry <= 1.0f - MARGIN);
    if (safe) {
      atomicAdd(&h[(int)fx * NB + (int)fy], 1u);
    } else {
      const uint32_t qi = atomicAdd(&qn, 1u);
      if (qi < QCAP) {
        q[qi] = (uint16_t)(s - base);
      } else {
        // overflow fallback (statistically unreachable): exact inline
        const uint32_t n = nbase + (uint32_t)s;
        const float xn = xv + tf_normal_(nk1a, nk1b, n) * 1e-4f;
        const float yn = yv + tf_normal_(nk2a, nk2b, n) * 1e-4f;
        const float vx = fminf(fmaxf((xn + 1.0f) * 0.5f, 0.001f), 0.999f);
        const float vy = fminf(fmaxf((yn + 1.0f) * 0.5f, 0.001f), 0.999f);
        int bx = (int)floorf(vx * 24.0f);
        int by = (int)floorf(vy * 24.0f);
        bx = bx < 0 ? 0 : (bx > 23 ? 23 : bx);
        by = by < 0 ? 0 : (by > 23 ? 23 : by);
        atomicAdd(&h[bx * NB + by], 1u);
      }
    }
  }
  __syncthreads();

  // Phase 2: dense exact path for boundary samples (all lanes active).
  const uint32_t nq = qn < QCAP ? qn : (uint32_t)QCAP;
  for (uint32_t j = tid; j < nq; j += HIST_THREADS) {
    const int s = base + (int)q[j];
    const int src = ((s >> 8) << 10) + ((s & 255) << 1);
    const uint32_t n = nbase + (uint32_t)s;
    const float xn = xb[src] + tf_normal_(nk1a, nk1b, n) * 1e-4f;
    const float yn = yb[src] + tf_normal_(nk2a, nk2b, n) * 1e-4f;
    const float vx = fminf(fmaxf((xn + 1.0f) * 0.5f, 0.001f), 0.999f);
    const float vy = fminf(fmaxf((yn + 1.0f) * 0.5f, 0.001f), 0.999f);
    int bx = (int)floorf(vx * 24.0f);
    int by = (int)floorf(vy * 24.0f);
    bx = bx < 0 ? 0 : (bx > 23 ? 23 : bx);
    by = by < 0 ? 0 : (by > 23 ? 23 : by);
    atomicAdd(&h[bx * NB + by], 1u);
  }
  __syncthreads();

  // Per-block partial histogram: plain coalesced stores, no atomics.
  uint32_t* gp = part + (size_t)blockIdx.x * NBINS;
  for (int t = tid; t < NBINS; t += HIST_THREADS) gp[t] = h[t];
}

// ONE block, 16 waves. Wave w handles batches w, w+16, w+32, w+48 with no
// inter-wave synchronization; single final barrier before the mean.
__global__ __launch_bounds__(1024) void nmi_reduce_kernel(
    const uint32_t* __restrict__ part, float* __restrict__ out) {
  __shared__ float joint[16][NBINS];   // per-wave scratch
  __shared__ float xh[16][NB];
  __shared__ float yh[16][NB];
  __shared__ float nmi_lds[NBATCH];

  const int tid  = threadIdx.x;
  const int w    = tid >> 6;           // wave id 0..15
  const int lane = tid & 63;

  for (int rb = 0; rb < NBATCH / 16; ++rb) {
    const int b = w + rb * 16;
    const uint32_t* pb = part + (size_t)b * HIST_BPB * NBINS;
    // Sum the 4 partials; 9 bins per lane (576 = 9*64), coalesced per wave.
    #pragma unroll
    for (int r = 0; r < NBINS / 64; ++r) {
      const int bin = lane + r * 64;
      uint32_t c = pb[bin] + pb[NBINS + bin] + pb[2 * NBINS + bin] +
                   pb[3 * NBINS + bin];
      joint[w][bin] = (float)c * (1.0f / 65536.0f);  // total==65536 exactly
    }
    // Wave-private LDS: ds ops are in-order per wave; no barrier needed.
    if (lane < NB) {
      float sx = 0.f;
      for (int j = 0; j < NB; ++j) sx += joint[w][lane * NB + j];
      xh[w][lane] = sx;
    } else if (lane >= 32 && lane < 32 + NB) {
      const int i = lane - 32;
      float sy = 0.f;
      for (int j = 0; j < NB; ++j) sy += joint[w][j * NB + i];
      yh[w][lane - 32] = sy;
    }
    float mi_part = 0.f;
    #pragma unroll
    for (int r = 0; r < NBINS / 64; ++r) {
      const int bin = lane + r * 64;
      const int i = (bin * 2731) >> 16;      // bin / 24 for bin < 576
      const int j = bin - i * NB;
      const float je = joint[w][bin] + 1e-5f;
      const float pe = (xh[w][i] + 1e-5f) * (yh[w][j] + 1e-5f);
      mi_part += je * (logf(je) - logf(pe));
    }
    float se_part = 0.f;
    if (lane < NB) {
      const float e = xh[w][lane] + 1e-5f;
      se_part = -(e * logf(e));              // hx term
    } else if (lane >= 32 && lane < 32 + NB) {
      const float e = yh[w][lane - 32] + 1e-5f;
      se_part = -(e * logf(e));              // hy term
    }
    for (int o = 32; o > 0; o >>= 1) {
      mi_part += __shfl_down(mi_part, o);
      se_part += __shfl_down(se_part, o);
    }
    if (lane == 0) {
      float nmi = (se_part < 1e-10f) ? 0.0f : (2.0f * mi_part / se_part);
      nmi_lds[b] = fminf(fmaxf(nmi, -1.0f), 1.0f);
    }
  }
  __syncthreads();

  if (tid < 64) {
    float v = nmi_lds[tid];
    for (int o = 32; o > 0; o >>= 1) v += __shfl_down(v, o);
    if (tid == 0) {
      float m = v * (1.0f / 64.0f);          // mean (exact /2^6)
      m = fminf(fmaxf(m, -1.0f), 1.0f);
      out[0] = -m;
    }
  }
}

extern "C" void kernel_launch(void* const* d_in, const int* in_sizes, int n_in,
                              void* d_out, int out_size, void* d_ws, size_t ws_size,
                              hipStream_t stream) {
  const float* x = (const float*)d_in[0];
  const float* y = (const float*)d_in[1];
  float* out = (float*)d_out;

  uint32_t* part = (uint32_t*)d_ws;  // 256 * 576 u32 = 589824 B

  // Host-side key derivation:
  // jax.random.split(jax.random.key(42)) under threefry_partitionable:
  //   nk_i = threefry2x32((0,42), count=(hi=0, lo=i)), both output words.
  uint32_t nk1a = 0u, nk1b = 0u; threefry2x32_(0u, 42u, nk1a, nk1b);
  uint32_t nk2a = 0u, nk2b = 1u; threefry2x32_(0u, 42u, nk2a, nk2b);

  nmi_hist_kernel<<<NBATCH * HIST_BPB, HIST_THREADS, 0, stream>>>(
      x, y, part, nk1a, nk1b, nk2a, nk2b);
  nmi_reduce_kernel<<<1, 1024, 0, stream>>>(part, out);
}

// Round 8
// 141.478 us; speedup vs baseline: 1.3147x; 1.0515x over previous
//
#include <hip/hip_runtime.h>
#include <stdint.h>
#include <stddef.h>

// NMI loss: x,y (64,1,512,512) f32 -> downsample ::2 -> +threefry noise*1e-4
// -> 24-bin joint hist per batch -> NMI -> -clip(mean,-1,1).
//
// Noise reproduces JAX's threefry2x32-20 stream (jax_threefry_partitionable
// default). Fast path: noise |delta_t| <= 6.54e-3 bin-units, so samples with
// frac(bin-coord) in [MARGIN, 1-MARGIN] are provably noise-invariant -> no
// threefry. Boundary samples (~3.2%) compact into an LDS queue, processed
// densely in phase 2 with the exact noisy path (verified absmax==0, R1-R7).
//
// R8: best-of-measured recombination.
//  - hist: R2's proven 1024 blocks x 512 thr shape (best total: 138.2us);
//    plain-store partials (R7-validated, kills the 147KB memset); block 0
//    zeroes the ticket counter (kills the memset launch entirely).
//  - reduce: R2's proven 64-block per-batch NMI + R4-validated 64-op
//    agent ticket for the final mean (R7's 1-block reduce idled 255 CUs,
//    ~ +10us; R3's 1024 tickets stalled L2 ~75us -- 64 is the sweet spot).

#define NB 24
#define NBINS 576          // 24*24
#define NBATCH 64
#define SPB 65536          // samples per batch = 256*256
#define HIST_BPB 16        // hist blocks per batch
#define HIST_THREADS 512
#define PER_BLOCK 4096     // SPB / HIST_BPB
#define QCAP 1024          // expected boundary load ~131/block
#define MARGIN 0.008f      // > 6.54e-3 worst-case noise swing in bin units

// ws layout: part (1024*576 u32) | gctr u32 | nmi f32[64]
#define PART_ELEMS (NBATCH * HIST_BPB * NBINS)
#define GCTR_OFF  ((size_t)PART_ELEMS * 4)     // 2359296
#define NMI_OFF   (GCTR_OFF + 256)

__host__ __device__ __forceinline__ uint32_t rotl32_(uint32_t x, uint32_t r) {
  return (x << r) | (x >> (32u - r));
}

// Threefry-2x32, 20 rounds (JAX semantics). x0,x1 carry counts in, bits out.
__host__ __device__ inline void threefry2x32_(uint32_t k0, uint32_t k1,
                                              uint32_t& x0, uint32_t& x1) {
  const uint32_t k2 = k0 ^ k1 ^ 0x1BD11BDAu;
  x0 += k0; x1 += k1;
#define TFR(r) { x0 += x1; x1 = rotl32_(x1, (r)); x1 ^= x0; }
  TFR(13u) TFR(15u) TFR(26u) TFR(6u)
  x0 += k1; x1 += k2 + 1u;
  TFR(17u) TFR(29u) TFR(16u) TFR(24u)
  x0 += k2; x1 += k0 + 2u;
  TFR(13u) TFR(15u) TFR(26u) TFR(6u)
  x0 += k0; x1 += k1 + 3u;
  TFR(17u) TFR(29u) TFR(16u) TFR(24u)
  x0 += k1; x1 += k2 + 4u;
  TFR(13u) TFR(15u) TFR(26u) TFR(6u)
  x0 += k2; x1 += k0 + 5u;
#undef TFR
}

// XLA ErfInv f32 (Giles polynomial) — matches jax.lax.erf_inv lowering.
__device__ __forceinline__ float erfinv32_(float x) {
  float w = -log1pf(-x * x);
  float p;
  if (w < 5.0f) {
    w -= 2.5f;
    p =  2.81022636e-08f;
    p = fmaf(p, w,  3.43273939e-07f);
    p = fmaf(p, w, -3.5233877e-06f);
    p = fmaf(p, w, -4.39150654e-06f);
    p = fmaf(p, w,  0.00021858087f);
    p = fmaf(p, w, -0.00125372503f);
    p = fmaf(p, w, -0.00417768164f);
    p = fmaf(p, w,  0.246640727f);
    p = fmaf(p, w,  1.50140941f);
  } else {
    w = sqrtf(w) - 3.0f;
    p = -0.000200214257f;
    p = fmaf(p, w,  0.000100950558f);
    p = fmaf(p, w,  0.00134934322f);
    p = fmaf(p, w, -0.00367342844f);
    p = fmaf(p, w,  0.00573950773f);
    p = fmaf(p, w, -0.0076224613f);
    p = fmaf(p, w,  0.00943887047f);
    p = fmaf(p, w,  1.00167406f);
    p = fmaf(p, w,  2.83297682f);
  }
  return p * x;
}

__device__ __forceinline__ float tf_normal_(uint32_t ka, uint32_t kb, uint32_t n) {
  uint32_t x0 = 0u, x1 = n;          // counter hi=0 (n < 2^32), lo=n
  threefry2x32_(ka, kb, x0, x1);
  const uint32_t bits = x0 ^ x1;     // 32-bit partitionable output
  float f = __uint_as_float((bits >> 9) | 0x3F800000u) - 1.0f;  // [0,1)
  const float lo = -0.99999994f;     // nextafter(-1,0) in f32
  float u = f * 2.0f + lo;           // f*(hi-lo)+lo, hi-lo rounds to 2.0f
  u = fmaxf(lo, u);
  return 1.41421356f * erfinv32_(u); // sqrt(2) in f32
}

__global__ __launch_bounds__(HIST_THREADS) void nmi_hist_kernel(
    const float* __restrict__ x, const float* __restrict__ y,
    uint32_t* __restrict__ part, uint32_t* __restrict__ gctr,
    uint32_t nk1a, uint32_t nk1b, uint32_t nk2a, uint32_t nk2b) {
  __shared__ uint32_t h[NBINS];
  __shared__ uint16_t q[QCAP];
  __shared__ uint32_t qn;
  const int tid = threadIdx.x;
  for (int t = tid; t < NBINS; t += HIST_THREADS) h[t] = 0u;
  if (tid == 0) qn = 0u;
  if (blockIdx.x == 0 && tid == 0) *gctr = 0u;  // end-of-kernel release
  __syncthreads();                              // makes this visible to k2

  const int b    = blockIdx.x / HIST_BPB;
  const int blk  = blockIdx.x % HIST_BPB;
  const int base = blk * PER_BLOCK;
  const float* __restrict__ xb = x + (size_t)b * 262144;  // 512*512
  const float* __restrict__ yb = y + (size_t)b * 262144;
  const uint32_t nbase = (uint32_t)b * (uint32_t)SPB;

  // Phase 1: fast path. Bin w/o noise; provably noise-invariant unless the
  // fractional bin coordinate is within MARGIN of a boundary.
  #pragma unroll
  for (int k = 0; k < PER_BLOCK / HIST_THREADS; ++k) {
    const int i = k * HIST_THREADS + tid;
    const int s = base + i;                    // sample index in [0, 65536)
    const int src = ((s >> 8) << 10) + ((s & 255) << 1);  // (2h)*512 + 2w
    const float xv = xb[src];
    const float yv = yb[src];
    const float tx = fminf(fmaxf((xv + 1.0f) * 0.5f, 0.001f), 0.999f) * 24.0f;
    const float ty = fminf(fmaxf((yv + 1.0f) * 0.5f, 0.001f), 0.999f) * 24.0f;
    const float fx = floorf(tx), fy = floorf(ty);
    const float rx = tx - fx,   ry = ty - fy;
    // t in [0.024, 23.976] -> (int)fx,(int)fy already in [0,23]
    const bool safe = (rx >= MARGIN) & (rx <= 1.0f - MARGIN) &
                      (ry >= MARGIN) & (ry <= 1.0f - MARGIN);
    if (safe) {
      atomicAdd(&h[(int)fx * NB + (int)fy], 1u);
    } else {
      const uint32_t qi = atomicAdd(&qn, 1u);
      if (qi < QCAP) {
        q[qi] = (uint16_t)i;
      } else {
        // overflow fallback (statistically unreachable): exact inline
        const uint32_t n = nbase + (uint32_t)s;
        const float xn = xv + tf_normal_(nk1a, nk1b, n) * 1e-4f;
        const float yn = yv + tf_normal_(nk2a, nk2b, n) * 1e-4f;
        const float vx = fminf(fmaxf((xn + 1.0f) * 0.5f, 0.001f), 0.999f);
        const float vy = fminf(fmaxf((yn + 1.0f) * 0.5f, 0.001f), 0.999f);
        int bx = (int)floorf(vx * 24.0f);
        int by = (int)floorf(vy * 24.0f);
        bx = bx < 0 ? 0 : (bx > 23 ? 23 : bx);
        by = by < 0 ? 0 : (by > 23 ? 23 : by);
        atomicAdd(&h[bx * NB + by], 1u);
      }
    }
  }
  __syncthreads();

  // Phase 2: dense exact path for boundary samples (all lanes active).
  const uint32_t nq = qn < QCAP ? qn : (uint32_t)QCAP;
  for (uint32_t j = tid; j < nq; j += HIST_THREADS) {
    const int i = (int)q[j];
    const int s = base + i;
    const int src = ((s >> 8) << 10) + ((s & 255) << 1);
    const uint32_t n = nbase + (uint32_t)s;
    const float xn = xb[src] + tf_normal_(nk1a, nk1b, n) * 1e-4f;
    const float yn = yb[src] + tf_normal_(nk2a, nk2b, n) * 1e-4f;
    const float vx = fminf(fmaxf((xn + 1.0f) * 0.5f, 0.001f), 0.999f);
    const float vy = fminf(fmaxf((yn + 1.0f) * 0.5f, 0.001f), 0.999f);
    int bx = (int)floorf(vx * 24.0f);
    int by = (int)floorf(vy * 24.0f);
    bx = bx < 0 ? 0 : (bx > 23 ? 23 : bx);
    by = by < 0 ? 0 : (by > 23 ? 23 : by);
    atomicAdd(&h[bx * NB + by], 1u);
  }
  __syncthreads();

  // Per-block partial histogram: plain coalesced stores, no atomics, no
  // pre-zeroed destination (R7-validated).
  uint32_t* gp = part + (size_t)blockIdx.x * NBINS;
  for (int t = tid; t < NBINS; t += HIST_THREADS) gp[t] = h[t];
}

// 64 blocks x 256 thr: per-batch NMI (R2-proven body) + R4-proven 64-op
// agent-ticket final mean.
__global__ __launch_bounds__(256) void nmi_reduce_kernel(
    const uint32_t* __restrict__ part, uint32_t* __restrict__ gctr,
    float* __restrict__ nmi_arr, float* __restrict__ out) {
  const int b = blockIdx.x;
  __shared__ float joint[NBINS];
  __shared__ float xh[NB];
  __shared__ float yh[NB];
  __shared__ float red_mi[4];
  __shared__ float red_h[4];
  __shared__ int glast;
  const int tid = threadIdx.x;

  const uint32_t* pb = part + (size_t)b * HIST_BPB * NBINS;
  for (int t = tid; t < NBINS; t += 256) {
    uint32_t c = 0;
    #pragma unroll
    for (int sb = 0; sb < HIST_BPB; ++sb) c += pb[sb * NBINS + t];
    joint[t] = (float)c * (1.0f / 65536.0f);   // total==65536 exactly
  }
  __syncthreads();

  if (tid < NB) {
    float sx = 0.f, sy = 0.f;
    for (int j = 0; j < NB; ++j) {
      sx += joint[tid * NB + j];   // x_hist
      sy += joint[j * NB + tid];   // y_hist
    }
    xh[tid] = sx; yh[tid] = sy;
  }
  __syncthreads();

  float mi_part = 0.f;
  for (int t = tid; t < NBINS; t += 256) {
    const int i = t / NB, j = t % NB;
    const float je = joint[t] + 1e-5f;
    const float pe = (xh[i] + 1e-5f) * (yh[j] + 1e-5f);
    mi_part += je * (logf(je) - logf(pe));
  }
  float h_part = 0.f;
  if (tid < NB) {
    const float e = xh[tid] + 1e-5f;
    h_part = -(e * logf(e));                        // hx term
  } else if (tid >= 64 && tid < 64 + NB) {
    const float e = yh[tid - 64] + 1e-5f;
    h_part = -(e * logf(e));                        // hy term
  }

  for (int o = 32; o > 0; o >>= 1) {
    mi_part += __shfl_down(mi_part, o);
    h_part  += __shfl_down(h_part, o);
  }
  const int wid  = tid >> 6;
  const int lane = tid & 63;
  if (lane == 0) { red_mi[wid] = mi_part; red_h[wid] = h_part; }
  __syncthreads();

  if (tid == 0) {
    const float mi = red_mi[0] + red_mi[1] + red_mi[2] + red_mi[3];
    const float se = red_h[0] + red_h[1] + red_h[2] + red_h[3];  // hx + hy
    float nmi = (se < 1e-10f) ? 0.0f : (2.0f * mi / se);
    nmi = fminf(fmaxf(nmi, -1.0f), 1.0f);
    __hip_atomic_store(&nmi_arr[b], nmi, __ATOMIC_RELEASE,
                       __HIP_MEMORY_SCOPE_AGENT);
    // 64 agent ACQ_REL ops total (R2/R4-proven cheap; 1024 was R3's stall).
    const uint32_t t2 = __hip_atomic_fetch_add(gctr, 1u, __ATOMIC_ACQ_REL,
                                               __HIP_MEMORY_SCOPE_AGENT);
    glast = (t2 == (uint32_t)(NBATCH - 1));
  }
  __syncthreads();

  if (glast && tid < 64) {
    float v = __hip_atomic_load(&nmi_arr[tid], __ATOMIC_ACQUIRE,
                                __HIP_MEMORY_SCOPE_AGENT);
    for (int o = 32; o > 0; o >>= 1) v += __shfl_down(v, o);
    if (tid == 0) {
      float m = v * (1.0f / 64.0f);                  // mean (exact /2^6)
      m = fminf(fmaxf(m, -1.0f), 1.0f);
      out[0] = -m;
    }
  }
}

extern "C" void kernel_launch(void* const* d_in, const int* in_sizes, int n_in,
                              void* d_out, int out_size, void* d_ws, size_t ws_size,
                              hipStream_t stream) {
  const float* x = (const float*)d_in[0];
  const float* y = (const float*)d_in[1];
  float* out = (float*)d_out;

  uint32_t* part = (uint32_t*)d_ws;
  uint32_t* gctr = (uint32_t*)((char*)d_ws + GCTR_OFF);
  float*    nmi  = (float*)((char*)d_ws + NMI_OFF);

  // Host-side key derivation:
  // jax.random.split(jax.random.key(42)) under threefry_partitionable:
  //   nk_i = threefry2x32((0,42), count=(hi=0, lo=i)), both output words.
  uint32_t nk1a = 0u, nk1b = 0u; threefry2x32_(0u, 42u, nk1a, nk1b);
  uint32_t nk2a = 0u, nk2b = 1u; threefry2x32_(0u, 42u, nk2a, nk2b);

  nmi_hist_kernel<<<NBATCH * HIST_BPB, HIST_THREADS, 0, stream>>>(
      x, y, part, gctr, nk1a, nk1b, nk2a, nk2b);
  nmi_reduce_kernel<<<NBATCH, 256, 0, stream>>>(part, gctr, nmi, out);
}